// Round 7
// baseline (1652.480 us; speedup 1.0000x reference)
//
#include <hip/hip_runtime.h>
#include <hip/hip_bf16.h>
#include <math.h>

#ifndef __has_builtin
#define __has_builtin(x) 0
#endif

typedef unsigned int uint;
typedef unsigned short ushort;
typedef _Float16 half2_t __attribute__((ext_vector_type(2)));

// Problem constants: B=64, T=512, V=30000, E=256, H=256, K=9. 4H = 1024.
// LSTM resident-W split: 90 k-pairs/gate as NAMED SCALARS (180 VGPRs),
// 38 k-pairs in LDS (152 KB). KEY (r6 post-mortem): __launch_bounds__(512,2)
// imposed a 128-VGPR cap (16 waves/CU budget) -> W spilled to scratch since
// r4. This round: __launch_bounds__(512,1) -> 256-VGPR budget.
#define PREG 90
#define WREG_UINTS (PREG * 2 * 512)        // 92160
#define WLDS_UINTS (19 * 512 * 4)          // 38912 (19 uint4-groups = 38 pairs)

__device__ __forceinline__ float sigm(float x) {
    return __fdividef(1.0f, 1.0f + __expf(-x));
}
__device__ __forceinline__ float tanh_fast(float x) {
    float sg = __fdividef(1.0f, 1.0f + __expf(-2.0f * x));
    return sg + sg - 1.0f;
}
__device__ __forceinline__ float dot2f(uint w, uint h, float acc) {
#if __has_builtin(__builtin_amdgcn_fdot2)
    return __builtin_amdgcn_fdot2(__builtin_bit_cast(half2_t, w),
                                  __builtin_bit_cast(half2_t, h), acc, false);
#else
    half2_t a = __builtin_bit_cast(half2_t, w);
    half2_t b = __builtin_bit_cast(half2_t, h);
    return acc + (float)a.x * (float)b.x + (float)a.y * (float)b.y;
#endif
}
__device__ __forceinline__ uint packh2(float a, float b) {
    ushort u0 = __builtin_bit_cast(ushort, (_Float16)a);
    ushort u1 = __builtin_bit_cast(ushort, (_Float16)b);
    return (uint)u0 | ((uint)u1 << 16);
}

// ---- preprocessor repetition ------------------------------------------------
#define R90(X) \
  X(0) X(1) X(2) X(3) X(4) X(5) X(6) X(7) \
  X(8) X(9) X(10) X(11) X(12) X(13) X(14) X(15) \
  X(16) X(17) X(18) X(19) X(20) X(21) X(22) X(23) \
  X(24) X(25) X(26) X(27) X(28) X(29) X(30) X(31) \
  X(32) X(33) X(34) X(35) X(36) X(37) X(38) X(39) \
  X(40) X(41) X(42) X(43) X(44) X(45) X(46) X(47) \
  X(48) X(49) X(50) X(51) X(52) X(53) X(54) X(55) \
  X(56) X(57) X(58) X(59) X(60) X(61) X(62) X(63) \
  X(64) X(65) X(66) X(67) X(68) X(69) X(70) X(71) \
  X(72) X(73) X(74) X(75) X(76) X(77) X(78) X(79) \
  X(80) X(81) X(82) X(83) X(84) X(85) X(86) X(87) \
  X(88) X(89)

#define R19(X) \
  X(0) X(1) X(2) X(3) X(4) X(5) X(6) X(7) \
  X(8) X(9) X(10) X(11) X(12) X(13) X(14) X(15) \
  X(16) X(17) X(18)

#define WDECL(m) uint wA##m, wB##m;
#define WLOAD(m) wA##m = wreg[(2 * (m)) * 512 + tid]; \
                 wB##m = wreg[(2 * (m) + 1) * 512 + tid];
#define WSTEP(m) { \
    uint hp = (uint)__builtin_amdgcn_readlane((int)((m) < 64 ? r0 : r1), (m) & 63); \
    aA = dot2f(wA##m, hp, aA); \
    aB = dot2f(wB##m, hp, aB); }
#define LSTEP(i) { \
    uint4 w4 = reinterpret_cast<const uint4*>(lw)[((i) << 9) + tid]; \
    uint hp0 = (uint)__builtin_amdgcn_readlane((int)r1, 26 + 2 * (i)); \
    uint hp1 = (uint)__builtin_amdgcn_readlane((int)r1, 27 + 2 * (i)); \
    aA = dot2f(w4.x, hp0, aA); \
    aB = dot2f(w4.y, hp0, aB); \
    aA = dot2f(w4.z, hp1, aA); \
    aB = dot2f(w4.w, hp1, aB); }

// ---------------------------------------------------------------------------
// zero_kernel: zero loss, preds, and feats rows with t >= len (masked region).
// ---------------------------------------------------------------------------
__global__ __launch_bounds__(256) void zero_kernel(float* __restrict__ out,
                                                   const int* __restrict__ lens) {
    int bid = blockIdx.x;
    if (bid < 65536) {
        int g = bid * 256 + threadIdx.x;
        int row = g >> 9;
        int t = row & 511;
        int b = row >> 9;
        if (t >= lens[b]) out[32769 + g] = 0.0f;
    } else if (bid < 65536 + 128) {
        int p = (bid - 65536) * 256 + threadIdx.x;
        out[1 + p] = 0.0f;
    } else if (threadIdx.x == 0) {
        out[0] = 0.0f;
    }
}

// ---------------------------------------------------------------------------
// pack_kernel: W_hh (4H,H) fp32 -> fp16 k-pair-packed. Thread tl=2j+s owns
// gates q=2s+x. Scalar chunk (m<90): wreg[(m*2+x)*512+tl]. LDS chunk
// (m=90..127): flat id2 = ((g*512+tl)*4 + c), m=90+2g+(c>>1), x=c&1.
// Per-direction ids: 92160 + 38912 = 131072. grid = 1024 x 256.
// ---------------------------------------------------------------------------
__global__ __launch_bounds__(256) void pack_kernel(const float* __restrict__ WF,
                                                   const float* __restrict__ WB,
                                                   uint* __restrict__ wregF,
                                                   uint* __restrict__ wregB,
                                                   uint* __restrict__ wldsF,
                                                   uint* __restrict__ wldsB) {
    int id = blockIdx.x * 256 + threadIdx.x;   // 0..262143
    const float* W = WF; uint* wr = wregF; uint* wl = wldsF;
    if (id >= 131072) { id -= 131072; W = WB; wr = wregB; wl = wldsB; }
    int m, x, tl, dst_lds = 0, id2 = 0;
    if (id < WREG_UINTS) {
        m = id >> 10;
        int r = id & 1023;
        x = r >> 9;
        tl = r & 511;
    } else {
        id2 = id - WREG_UINTS;            // 0..38911
        int c = id2 & 3;
        int u = id2 >> 2;
        tl = u & 511;
        int g = u >> 9;                   // 0..18
        m = PREG + 2 * g + (c >> 1);
        x = c & 1;
        dst_lds = 1;
    }
    int j = tl >> 1, s = tl & 1;
    int q = (s << 1) + x;
    const float* row = W + ((size_t)((q << 8) + j) << 8);
    uint pk = packh2(row[2 * m], row[2 * m + 1]);
    if (dst_lds) wl[id2] = pk;
    else         wr[((m << 1) + x) * 512 + tl] = pk;
}

// ---------------------------------------------------------------------------
// wih_pack_kernel: Wih fp32 -> fp16 k-pair packed, indexed by interleaved
// output column: wih16[col*128 + p], perm(col) = (col&3)*256 + (col>>2).
// ---------------------------------------------------------------------------
__global__ __launch_bounds__(256) void wih_pack_kernel(const float* __restrict__ WihF,
                                                       const float* __restrict__ WihB,
                                                       uint* __restrict__ w16F,
                                                       uint* __restrict__ w16B) {
    int id = blockIdx.x * 256 + threadIdx.x;   // 0..262143
    const float* W = WihF; uint* dst = w16F;
    if (id >= 131072) { id -= 131072; W = WihB; dst = w16B; }
    int col = id >> 7;
    int p = id & 127;
    int perm = ((col & 3) << 8) + (col >> 2);
    const float* row = W + ((size_t)perm << 8);
    dst[(col << 7) + p] = packh2(row[2 * p], row[2 * p + 1]);
}

// ---------------------------------------------------------------------------
// gemm_gx: fp16-pair dot2 GEMM. gx_il[row][col] = emb[row].Wih[perm(col)] +
// bias[perm(col)]. 64x64 tile, 32 k per iter, 4x4/thread. Skips masked tiles.
// grid = (512, 16)
// ---------------------------------------------------------------------------
__global__ __launch_bounds__(256) void gemm_gx_kernel(const int* __restrict__ widx,
                                                      const int* __restrict__ lens,
                                                      const float* __restrict__ wvec,
                                                      const uint* __restrict__ wih16,
                                                      const float* __restrict__ bias,
                                                      _Float16* __restrict__ gx) {
    int row0 = blockIdx.x * 64;
    int b = row0 >> 9;
    int t0 = row0 & 511;
    if (t0 >= lens[b]) return;
    int n0 = blockIdx.y * 64;

    __shared__ __align__(16) uint As[16][68];
    __shared__ __align__(16) uint Bs[16][68];
    __shared__ int aoff[64];

    int tid = threadIdx.x;
    if (tid < 64) aoff[tid] = widx[row0 + tid] << 8;
    __syncthreads();

    float acc[4][4] = {};
    int tn = tid & 15, tm = tid >> 4;

    for (int k0p = 0; k0p < 128; k0p += 16) {
#pragma unroll
        for (int p = 0; p < 4; ++p) {
            int lin = p * 256 + tid;
            int kp = lin & 15, m = lin >> 4;
            const float2 av = *reinterpret_cast<const float2*>(
                &wvec[aoff[m] + ((k0p + kp) << 1)]);
            As[kp][m] = packh2(av.x, av.y);
            Bs[kp][m] = wih16[((n0 + m) << 7) + k0p + kp];
        }
        __syncthreads();
#pragma unroll
        for (int kp = 0; kp < 16; ++kp) {
            uint4 a4 = *reinterpret_cast<const uint4*>(&As[kp][tm * 4]);
            uint4 b4 = *reinterpret_cast<const uint4*>(&Bs[kp][tn * 4]);
            uint am[4] = {a4.x, a4.y, a4.z, a4.w};
            uint bn[4] = {b4.x, b4.y, b4.z, b4.w};
#pragma unroll
            for (int i = 0; i < 4; ++i)
#pragma unroll
                for (int j = 0; j < 4; ++j) acc[i][j] = dot2f(am[i], bn[j], acc[i][j]);
        }
        __syncthreads();
    }

#pragma unroll
    for (int i = 0; i < 4; ++i) {
        int row = row0 + tm * 4 + i;
        ushort u[4];
#pragma unroll
        for (int j = 0; j < 4; ++j) {
            int col = n0 + tn * 4 + j;
            int perm = ((col & 3) << 8) + (col >> 2);
            u[j] = __builtin_bit_cast(ushort, (_Float16)(acc[i][j] + bias[perm]));
        }
        uint2 st;
        st.x = (uint)u[0] | ((uint)u[1] << 16);
        st.y = (uint)u[2] | ((uint)u[3] << 16);
        *reinterpret_cast<uint2*>(&gx[row * 1024 + n0 + tn * 4]) = st;
    }
}

// ---------------------------------------------------------------------------
// lstm_kernel: one block per (b, dir); 512 threads. Thread 2j+s owns gate
// rows {2s, 2s+1} of hidden j. W_hh fp16 resident: 90 k-pairs/gate as 180
// named scalar uints in VGPRs + 38 k-pairs in LDS (152 KB, ds_read_b128).
// __launch_bounds__(512, 1): 8 waves/CU -> 256-VGPR budget (the (512,2)
// declaration capped at 128 and silently spilled W to scratch, r4-r6).
// h broadcast via v_readlane; gate halves exchanged via __shfl_xor.
// ---------------------------------------------------------------------------
__global__ __launch_bounds__(512, 1) void lstm_kernel(const _Float16* __restrict__ gx0,
                                                      const _Float16* __restrict__ gx1,
                                                      const uint* __restrict__ wreg0,
                                                      const uint* __restrict__ wreg1,
                                                      const uint* __restrict__ wlds0,
                                                      const uint* __restrict__ wlds1,
                                                      const int* __restrict__ lens,
                                                      float* __restrict__ feats) {
    int dir = blockIdx.x & 1;
    int b = blockIdx.x >> 1;
    const uint* gxu = reinterpret_cast<const uint*>(dir ? gx1 : gx0) + ((size_t)(b << 9) << 9);
    const uint* wreg = dir ? wreg1 : wreg0;
    const uint* wlds = dir ? wlds1 : wlds0;
    int len = lens[b];
    int tid = threadIdx.x;
    int lane = tid & 63;
    int sg = tid & 1;

    __shared__ __align__(16) uint lw[WLDS_UINTS];    // 152 KB LDS W chunk
    __shared__ __align__(16) uint hpair[2][128];     // fp16-pair h, dbuf

    for (int i = tid; i < WLDS_UINTS; i += 512) lw[i] = wlds[i];

    R90(WDECL)            // uint wA0..wA89, wB0..wB89 — named scalars
    R90(WLOAD)
    __syncthreads();

    float c = 0.0f;
    uint r0 = 0, r1 = 0;
    int pp = 0;

    int t0i = dir ? (len - 1) : 0;
    uint g = gxu[(t0i << 9) + tid];

    for (int tp = 0; tp < len; ++tp) {
        int t = dir ? (len - 1 - tp) : tp;
        int tnn = dir ? (len - 2 - tp) : (tp + 1);
        tnn = tnn < 0 ? 0 : (tnn >= len ? len - 1 : tnn);
        uint gnext = gxu[(tnn << 9) + tid];

        half2_t gv = __builtin_bit_cast(half2_t, g);
        float aA = (float)gv.x;
        float aB = (float)gv.y;

        R90(WSTEP)        // k-pairs 0..89: W in VGPRs, h via readlane
        R19(LSTEP)        // k-pairs 90..127: W in LDS

        // s=0: pA=sigm(i), pB=sigm(f) ; s=1: pA=tanh(g), pB=sigm(o)
        float y = sg ? aA + aA : aA;
        float sgm = __fdividef(1.0f, 1.0f + __expf(-y));
        float pA = sg ? sgm + sgm - 1.0f : sgm;
        float pB = sigm(aB);

        float oA = __shfl_xor(pA, 1);
        float oB = __shfl_xor(pB, 1);
        float si = sg ? oA : pA;
        float sf = sg ? oB : pB;
        float tg = sg ? pA : oA;
        float so = sg ? pB : oB;

        c = sf * c + si * tg;
        float h = so * tanh_fast(c);

        if (!sg) {
            reinterpret_cast<ushort*>(hpair[pp])[tid >> 1] =
                __builtin_bit_cast(ushort, (_Float16)h);
            feats[(size_t)(((b << 9) + t)) * 512 + (dir << 8) + (tid >> 1)] = h;
        }
        __syncthreads();
        r0 = hpair[pp][lane];
        r1 = hpair[pp][64 + lane];
        pp ^= 1;
        g = gnext;
    }
}

// ---------------------------------------------------------------------------
// emis_kernel: emissions[b,t,k] = feats[b,t,:] . W_out[k,:] + b_out[k]
// ---------------------------------------------------------------------------
__global__ __launch_bounds__(64) void emis_kernel(const float* __restrict__ feats,
                                                  const float* __restrict__ Wout,
                                                  const float* __restrict__ bout,
                                                  const int* __restrict__ lens,
                                                  float* __restrict__ emis) {
    int r = blockIdx.x;
    int b = r >> 9, t = r & 511;
    if (t >= lens[b]) return;
    int lane = threadIdx.x;
    const float* fr = feats + (size_t)r * 512;
    float f[8];
#pragma unroll
    for (int i = 0; i < 8; ++i) f[i] = fr[i * 64 + lane];
#pragma unroll
    for (int k = 0; k < 9; ++k) {
        float p = 0.0f;
#pragma unroll
        for (int i = 0; i < 8; ++i) p = fmaf(f[i], Wout[k * 512 + i * 64 + lane], p);
#pragma unroll
        for (int off = 32; off; off >>= 1) p += __shfl_down(p, off);
        if (lane == 0) emis[r * 9 + k] = p + bout[k];
    }
}

// ---------------------------------------------------------------------------
// crf_kernel: alpha recursion + viterbi + backtrace + numerator + loss.
// ---------------------------------------------------------------------------
__global__ __launch_bounds__(64) void crf_kernel(const float* __restrict__ emis,
                                                 const int* __restrict__ lens,
                                                 const int* __restrict__ labels,
                                                 const float* __restrict__ start_trans,
                                                 const float* __restrict__ end_trans,
                                                 const float* __restrict__ trans,
                                                 float* __restrict__ out) {
    int b = blockIdx.x;
    int len = lens[b];
    int lane = threadIdx.x;
    __shared__ float alpha[9], vit[9];
    __shared__ unsigned char hist[512 * 9];
    const float* eb = emis + b * 512 * 9;
    const int* lb = labels + b * 512;

    float tr[9];
    if (lane < 9) {
#pragma unroll
        for (int i = 0; i < 9; ++i) tr[i] = trans[i * 9 + lane];
        float s0 = start_trans[lane] + eb[lane];
        alpha[lane] = s0;
        vit[lane] = s0;
    }
    __syncthreads();

    for (int t = 1; t < len; ++t) {
        float na = 0.0f, nv = 0.0f;
        if (lane < 9) {
            float e = eb[t * 9 + lane];
            float a[9];
#pragma unroll
            for (int i = 0; i < 9; ++i) a[i] = alpha[i] + tr[i];
            float m = a[0];
#pragma unroll
            for (int i = 1; i < 9; ++i) m = fmaxf(m, a[i]);
            float s = 0.0f;
#pragma unroll
            for (int i = 0; i < 9; ++i) s += __expf(a[i] - m);
            na = m + __logf(s) + e;
            float bv = vit[0] + tr[0];
            int bi = 0;
#pragma unroll
            for (int i = 1; i < 9; ++i) {
                float x = vit[i] + tr[i];
                if (x > bv) { bv = x; bi = i; }
            }
            nv = bv + e;
            hist[t * 9 + lane] = (unsigned char)bi;
        }
        __syncthreads();
        if (lane < 9) { alpha[lane] = na; vit[lane] = nv; }
        __syncthreads();
    }

    float part = 0.0f;
    for (int t = 1 + lane; t < len; t += 64) {
        int yp = lb[t - 1], y = lb[t];
        part += trans[yp * 9 + y] + eb[t * 9 + y];
    }
#pragma unroll
    for (int off = 32; off; off >>= 1) part += __shfl_down(part, off);

    if (lane == 0) {
        int y0 = lb[0];
        float num = start_trans[y0] + eb[y0] + part + end_trans[lb[len - 1]];
        float m = alpha[0] + end_trans[0];
        for (int j = 1; j < 9; ++j) m = fmaxf(m, alpha[j] + end_trans[j]);
        float s = 0.0f;
        for (int j = 0; j < 9; ++j) s += __expf(alpha[j] + end_trans[j] - m);
        float denom = m + __logf(s);
        atomicAdd(out, (denom - num) * (1.0f / 64.0f));

        float bm = vit[0] + end_trans[0];
        int cur = 0;
        for (int j = 1; j < 9; ++j) {
            float x = vit[j] + end_trans[j];
            if (x > bm) { bm = x; cur = j; }
        }
        float* preds = out + 1 + b * 512;
        preds[len - 1] = (float)cur;
        for (int t = len - 1; t >= 1; --t) {
            cur = hist[t * 9 + cur];
            preds[t - 1] = (float)cur;
        }
    }
}

// ---------------------------------------------------------------------------
extern "C" void kernel_launch(void* const* d_in, const int* in_sizes, int n_in,
                              void* d_out, int out_size, void* d_ws, size_t ws_size,
                              hipStream_t stream) {
    const int* widx = (const int*)d_in[0];
    const int* lens = (const int*)d_in[1];
    const int* labels = (const int*)d_in[2];
    const float* wvec = (const float*)d_in[3];
    const float* WihF = (const float*)d_in[4];
    const float* WhhF = (const float*)d_in[5];
    const float* bF = (const float*)d_in[6];
    const float* WihB = (const float*)d_in[7];
    const float* WhhB = (const float*)d_in[8];
    const float* bB = (const float*)d_in[9];
    const float* Wout = (const float*)d_in[10];
    const float* bout = (const float*)d_in[11];
    const float* start_trans = (const float*)d_in[12];
    const float* end_trans = (const float*)d_in[13];
    const float* trans9 = (const float*)d_in[14];
    float* out = (float*)d_out;
    char* ws = (char*)d_ws;

    // workspace layout (bytes)
    _Float16* gxF = (_Float16*)(ws);                        // 67,108,864
    _Float16* gxB = (_Float16*)(ws + 67108864);             // 67,108,864
    uint* wregF   = (uint*)(ws + 134217728);                // 368,640
    uint* wregB   = (uint*)(ws + 134586368);                // 368,640
    uint* wldsF   = (uint*)(ws + 134955008);                // 155,648
    uint* wldsB   = (uint*)(ws + 135110656);                // 155,648
    // wih16F/B live only before lstm; emis written after lstm -> safe alias
    uint* wih16F  = (uint*)(ws + 135266304);                // 524,288
    uint* wih16B  = (uint*)(ws + 135790592);                // 524,288
    float* emis   = (float*)(ws + 135266304);               // 1,179,648 (alias)
    (void)in_sizes; (void)n_in; (void)out_size; (void)ws_size;

    float* feats = out + 1 + 32768;   // feats output region (B,T,512) fp32

    zero_kernel<<<65665, 256, 0, stream>>>(out, lens);
    pack_kernel<<<1024, 256, 0, stream>>>(WhhF, WhhB, wregF, wregB, wldsF, wldsB);
    wih_pack_kernel<<<1024, 256, 0, stream>>>(WihF, WihB, wih16F, wih16B);

    dim3 ggrid(512, 16);
    gemm_gx_kernel<<<ggrid, 256, 0, stream>>>(widx, lens, wvec, wih16F, bF, gxF);
    gemm_gx_kernel<<<ggrid, 256, 0, stream>>>(widx, lens, wvec, wih16B, bB, gxB);

    lstm_kernel<<<128, 512, 0, stream>>>(gxF, gxB, wregF, wregB, wldsF, wldsB, lens, feats);

    emis_kernel<<<32768, 64, 0, stream>>>(feats, Wout, bout, lens, emis);
    crf_kernel<<<64, 64, 0, stream>>>(emis, lens, labels, start_trans, end_trans, trans9, out);
}